// Round 7
// baseline (1839.552 us; speedup 1.0000x reference)
//
#include <hip/hip_runtime.h>
#include <hip/hip_bf16.h>
#include <math.h>

#define N_Q 2048
#define K_E 32
#define D_F 128
#define H_N 8
#define DH_N 16
#define EPS_F 1e-5f
#define NEGMAX -3.4028235e38f

// NOTE (round 6 lesson): inputs are fp32 AND the reference output is fp32, so
// d_out is float*. Writing bf16 here was the sole bug from rounds 2-6.

// ---------------------------------------------------------------------------
// Kernel A: query eq_layer_norm + eq_linear(Wq); writes qs2/qv2 and skip_s/v
// one block per n, 128 threads (thread = output feature)
// ---------------------------------------------------------------------------
__global__ __launch_bounds__(128) void k_query(
    const float* __restrict__ qs_in, const float* __restrict__ qv_in,
    const float* __restrict__ Wq_s, const float* __restrict__ Wq_v,
    const float* __restrict__ bq,
    const float* __restrict__ ln_gs, const float* __restrict__ ln_bs,
    const float* __restrict__ ln_gv,
    float* __restrict__ qs2, float* __restrict__ qv2,
    float* __restrict__ skip_s, float* __restrict__ skip_v)
{
    const int n = blockIdx.x, t = threadIdx.x;
    __shared__ float s[D_F], v[D_F*3], sl[D_F], vl[D_F*3];
    s[t] = qs_in[n*D_F + t];
    #pragma unroll
    for (int x = 0; x < 3; ++x) v[t*3+x] = qv_in[(n*D_F + t)*3 + x];
    __syncthreads();
    float mu = 0.f;
    for (int i = 0; i < D_F; ++i) mu += s[i];
    mu *= (1.f/D_F);
    float var = 0.f;
    for (int i = 0; i < D_F; ++i) { float d = s[i]-mu; var += d*d; }
    var *= (1.f/D_F);
    float rstd = rsqrtf(var + EPS_F);
    float ssq = 0.f;
    for (int i = 0; i < D_F*3; ++i) ssq += v[i]*v[i];
    float rrms = rsqrtf(ssq*(1.f/D_F) + EPS_F);
    float a = (s[t]-mu)*rstd*ln_gs[t] + ln_bs[t];
    sl[t] = a; skip_s[n*D_F + t] = a;
    float gv = ln_gv[t];
    #pragma unroll
    for (int x = 0; x < 3; ++x) {
        float b = v[t*3+x]*rrms*gv;
        vl[t*3+x] = b; skip_v[(n*D_F + t)*3 + x] = b;
    }
    __syncthreads();
    float acc = bq[t], a0 = 0.f, a1 = 0.f, a2 = 0.f;
    for (int i = 0; i < D_F; ++i) {
        float ws = Wq_s[i*D_F + t]; acc += sl[i]*ws;
        float wv = Wq_v[i*D_F + t];
        a0 += vl[i*3+0]*wv; a1 += vl[i*3+1]*wv; a2 += vl[i*3+2]*wv;
    }
    qs2[n*D_F + t] = acc;
    qv2[(n*D_F + t)*3 + 0] = a0;
    qv2[(n*D_F + t)*3 + 1] = a1;
    qv2[(n*D_F + t)*3 + 2] = a2;
}

// ---------------------------------------------------------------------------
// Kernel B: key eq_linear(Wk) for all N keys (no LN on key path)
// ---------------------------------------------------------------------------
__global__ __launch_bounds__(128) void k_key(
    const float* __restrict__ ks_in, const float* __restrict__ kv_in,
    const float* __restrict__ Wk_s, const float* __restrict__ Wk_v,
    const float* __restrict__ bk,
    float* __restrict__ ksc, float* __restrict__ kvc)
{
    const int n = blockIdx.x, t = threadIdx.x;
    __shared__ float s[D_F], v[D_F*3];
    s[t] = ks_in[n*D_F + t];
    #pragma unroll
    for (int x = 0; x < 3; ++x) v[t*3+x] = kv_in[(n*D_F + t)*3 + x];
    __syncthreads();
    float acc = bk[t], a0 = 0.f, a1 = 0.f, a2 = 0.f;
    for (int i = 0; i < D_F; ++i) {
        float ws = Wk_s[i*D_F + t]; acc += s[i]*ws;
        float wv = Wk_v[i*D_F + t];
        a0 += v[i*3+0]*wv; a1 += v[i*3+1]*wv; a2 += v[i*3+2]*wv;
    }
    ksc[n*D_F + t] = acc;
    kvc[(n*D_F + t)*3 + 0] = a0;
    kvc[(n*D_F + t)*3 + 1] = a1;
    kvc[(n*D_F + t)*3 + 2] = a2;
}

// ---------------------------------------------------------------------------
// Kernel C: fused per-query edge pipeline, online softmax, register acc.
// one block per n, 256 threads
// ---------------------------------------------------------------------------
__global__ __launch_bounds__(256) void k_edge(
    const float* __restrict__ qs2, const float* __restrict__ qv2,
    const float* __restrict__ ksc, const float* __restrict__ kvc,
    const float* __restrict__ eis, const float* __restrict__ eiv,
    const float* __restrict__ eemb,
    const int* __restrict__ mask, const int* __restrict__ knn,
    const float* __restrict__ Wqk_s, const float* __restrict__ Wqk_v, const float* __restrict__ bqk,
    const float* __restrict__ Wdtp, const float* __restrict__ bdtp,
    const float* __restrict__ Wagv_s, const float* __restrict__ bagv, const float* __restrict__ Wagv_v,
    const float* __restrict__ Wattn, const float* __restrict__ lna_g, const float* __restrict__ lna_b,
    const float* __restrict__ Wval_s, const float* __restrict__ Wval_v, const float* __restrict__ bval,
    float* __restrict__ outs_pre, float* __restrict__ outv_pre,
    float* __restrict__ attn_out)
{
    const int n = blockIdx.x, t = threadIdx.x;

    __shared__ float sh_qs[D_F], sh_qv[D_F*3];
    __shared__ float sh_ks[D_F], sh_kv[D_F*3], sh_ee[D_F];
    __shared__ float sh_cs[2*D_F], sh_cv[2*D_F*3];
    __shared__ float sh_ps[D_F], sh_pv[D_F*3];
    __shared__ float sh_w[4*D_F];
    __shared__ float sh_agv[H_N*48], sh_valv[H_N*DH_N*3];
    __shared__ float sh_logit[H_N*K_E], sh_red[H_N*2];
    __shared__ float sh_es, sh_ev[3];

    float m_run = NEGMAX, l_run = 0.f;                    // t<8: per-head softmax state
    float accs = 0.f, acc0 = 0.f, acc1 = 0.f, acc2 = 0.f; // t<128: output accumulators

    if (t < D_F) sh_qs[t] = qs2[n*D_F + t];
    for (int idx = t; idx < D_F*3; idx += 256) sh_qv[idx] = qv2[n*D_F*3 + idx];

    for (int k = 0; k < K_E; ++k) {
        const int e = n*K_E + k;
        const int j = knn[e];
        if (t < D_F) { sh_ks[t] = ksc[j*D_F + t]; sh_ee[t] = eemb[e*D_F + t]; }
        for (int idx = t; idx < D_F*3; idx += 256) sh_kv[idx] = kvc[j*D_F*3 + idx];
        if (t == 0) {
            sh_es = eis[e];
            sh_ev[0] = eiv[e*3+0]; sh_ev[1] = eiv[e*3+1]; sh_ev[2] = eiv[e*3+2];
        }
        __syncthreads();

        // dtp #1: q (x) gathered k.  cat c: [0,128)=ss/sv, [128,256)=vv/vs
        {
            const int c = t;
            if (c < D_F) {
                float s1 = sh_qs[c];
                sh_cs[c] = s1 * sh_ks[c];
                #pragma unroll
                for (int x = 0; x < 3; ++x) sh_cv[c*3+x] = s1 * sh_kv[c*3+x];
            } else {
                int d = c - D_F;
                float dot = 0.f;
                #pragma unroll
                for (int x = 0; x < 3; ++x) dot += sh_qv[d*3+x]*sh_kv[d*3+x];
                sh_cs[c] = dot;
                #pragma unroll
                for (int x = 0; x < 3; ++x) sh_cv[c*3+x] = sh_ks[d]*sh_qv[d*3+x];
            }
        }
        __syncthreads();

        // w = edge_emb @ Wdtp + bdtp (512 outputs, 2 per thread)
        #pragma unroll
        for (int r = 0; r < 2; ++r) {
            int o = t + r*256;
            float acc = bdtp[o];
            for (int i = 0; i < D_F; ++i) acc += sh_ee[i]*Wdtp[i*512 + o];
            sh_w[o] = acc;
        }
        // Wqk per-head linear (head h input i = cat channel h*32+i)
        if (t < D_F) {
            int h = t >> 4, o = t & 15;
            float as = bqk[o], av0 = 0.f, av1 = 0.f, av2 = 0.f;
            for (int i = 0; i < 32; ++i) {
                int cb = h*32 + i;
                float ws = Wqk_s[i*16 + o];
                as += sh_cs[cb]*ws;
                float wv = Wqk_v[i*16 + o];
                av0 += sh_cv[cb*3+0]*wv;
                av1 += sh_cv[cb*3+1]*wv;
                av2 += sh_cv[cb*3+2]*wv;
            }
            sh_ps[t] = as;
            sh_pv[t*3+0] = av0; sh_pv[t*3+1] = av1; sh_pv[t*3+2] = av2;
        }
        __syncthreads();

        // dtp #2 (weighted, vs edge irreps); w index: sel*128 + h*16 + c
        {
            int h = t >> 5, i = t & 31;
            float es = sh_es;
            if (i < DH_N) {
                int cc = h*DH_N + i;
                float s1 = sh_ps[cc];
                sh_cs[t] = s1*es*sh_w[0*D_F + cc];
                float w2 = sh_w[2*D_F + cc];
                #pragma unroll
                for (int x = 0; x < 3; ++x) sh_cv[t*3+x] = s1*sh_ev[x]*w2;
            } else {
                int cc = h*DH_N + (i - DH_N);
                float dot = 0.f;
                #pragma unroll
                for (int x = 0; x < 3; ++x) dot += sh_pv[cc*3+x]*sh_ev[x];
                sh_cs[t] = dot*sh_w[1*D_F + cc];
                float w3 = sh_w[3*D_F + cc];
                #pragma unroll
                for (int x = 0; x < 3; ++x) sh_cv[t*3+x] = es*sh_pv[cc*3+x]*w3;
            }
        }
        __syncthreads();

        // Wagv: agv (H x 48) and val_v (H x 16 x 3)
        for (int idx = t; idx < H_N*48; idx += 256) {
            int h = idx / 48, o = idx % 48;
            float acc = bagv[h*48 + o];
            for (int i = 0; i < 32; ++i)
                acc += sh_cs[h*32 + i]*Wagv_s[(h*32 + i)*48 + o];
            sh_agv[idx] = acc;
        }
        if (t < D_F) {
            int h = t >> 4, o = t & 15;
            float a0 = 0.f, a1 = 0.f, a2 = 0.f;
            for (int i = 0; i < 32; ++i) {
                float wv = Wagv_v[(h*32 + i)*16 + o];
                a0 += sh_cv[(h*32+i)*3+0]*wv;
                a1 += sh_cv[(h*32+i)*3+1]*wv;
                a2 += sh_cv[(h*32+i)*3+2]*wv;
            }
            sh_valv[t*3+0] = a0; sh_valv[t*3+1] = a1; sh_valv[t*3+2] = a2;
        }
        __syncthreads();

        // logit + online softmax update (t<8); silu/sigmoid gating (t<128)
        if (t < H_N) {
            const float* af = &sh_agv[t*48];
            float mu = 0.f;
            for (int d2 = 0; d2 < DH_N; ++d2) mu += af[d2];
            mu *= (1.f/DH_N);
            float var = 0.f;
            for (int d2 = 0; d2 < DH_N; ++d2) { float dd = af[d2]-mu; var += dd*dd; }
            var *= (1.f/DH_N);
            float rstd = rsqrtf(var + EPS_F);
            float logit = 0.f;
            for (int d2 = 0; d2 < DH_N; ++d2) {
                float xn = (af[d2]-mu)*rstd*lna_g[d2] + lna_b[d2];
                logit += xn*Wattn[d2];
            }
            if (mask[e] == 0) logit = NEGMAX;
            sh_logit[t*K_E + k] = logit;
            float m_new = fmaxf(m_run, logit);
            float alpha = expf(m_run - m_new);
            float p     = expf(logit - m_new);
            l_run = l_run*alpha + p;
            m_run = m_new;
            sh_red[t*2]   = alpha;
            sh_red[t*2+1] = p;
        }
        if (t < D_F) {
            int h = t >> 4, o = t & 15;
            float vraw = sh_agv[h*48 + 32 + o];
            float sact = vraw / (1.f + expf(-vraw));
            float g = 1.f / (1.f + expf(-sh_agv[h*48 + 16 + o]));
            sh_ps[t] = sact;
            #pragma unroll
            for (int x = 0; x < 3; ++x) sh_pv[t*3+x] = sh_valv[t*3+x]*g;
        }
        __syncthreads();

        // dtp #3 (unweighted, vs edge irreps)
        {
            int h = t >> 5, i = t & 31;
            if (i < DH_N) {
                int cc = h*DH_N + i;
                float s1 = sh_ps[cc];
                sh_cs[t] = s1*sh_es;
                #pragma unroll
                for (int x = 0; x < 3; ++x) sh_cv[t*3+x] = s1*sh_ev[x];
            } else {
                int cc = h*DH_N + (i - DH_N);
                float dot = 0.f;
                #pragma unroll
                for (int x = 0; x < 3; ++x) dot += sh_pv[cc*3+x]*sh_ev[x];
                sh_cs[t] = dot;
                #pragma unroll
                for (int x = 0; x < 3; ++x) sh_cv[t*3+x] = sh_es*sh_pv[cc*3+x];
            }
        }
        __syncthreads();

        // Wval + flash-style accumulate: acc = acc*alpha + p*val
        if (t < D_F) {
            int h = t >> 4, o = t & 15;
            float vs = bval[o], v0 = 0.f, v1 = 0.f, v2 = 0.f;
            for (int i = 0; i < 32; ++i) {
                int cb = h*32 + i;
                float ws = Wval_s[i*16 + o];
                vs += sh_cs[cb]*ws;
                float wv = Wval_v[i*16 + o];
                v0 += sh_cv[cb*3+0]*wv;
                v1 += sh_cv[cb*3+1]*wv;
                v2 += sh_cv[cb*3+2]*wv;
            }
            float alpha = sh_red[h*2], p = sh_red[h*2+1];
            accs = accs*alpha + p*vs;
            acc0 = acc0*alpha + p*v0;
            acc1 = acc1*alpha + p*v1;
            acc2 = acc2*alpha + p*v2;
        }
        __syncthreads();   // protect sh_red + sh_cs/cv before next iteration
    }

    // epilogue: finalize softmax, write attn + weighted sums (all fp32)
    if (t < H_N) {
        sh_red[t*2]   = m_run;
        sh_red[t*2+1] = 1.f / l_run;
    }
    __syncthreads();
    {
        int h = t >> 5, k = t & 31;
        float a = expf(sh_logit[t] - sh_red[h*2]) * sh_red[h*2+1];
        attn_out[h*(N_Q*K_E) + n*K_E + k] = a;
    }
    if (t < D_F) {
        int h = t >> 4;
        float rinv = sh_red[h*2+1];
        outs_pre[n*D_F + t]     = accs*rinv;
        outv_pre[(n*D_F+t)*3+0] = acc0*rinv;
        outv_pre[(n*D_F+t)*3+1] = acc1*rinv;
        outv_pre[(n*D_F+t)*3+2] = acc2*rinv;
    }
}

// ---------------------------------------------------------------------------
// Kernel D: output eq_linear(Wo) + skip add, fp32 outputs
// ---------------------------------------------------------------------------
__global__ __launch_bounds__(128) void k_out(
    const float* __restrict__ outs_pre, const float* __restrict__ outv_pre,
    const float* __restrict__ skip_s, const float* __restrict__ skip_v,
    const float* __restrict__ Wo_s, const float* __restrict__ Wo_v, const float* __restrict__ bo,
    float* __restrict__ out0, float* __restrict__ out1)
{
    const int n = blockIdx.x, t = threadIdx.x;
    __shared__ float ps[D_F], pv[D_F*3];
    ps[t] = outs_pre[n*D_F + t];
    #pragma unroll
    for (int x = 0; x < 3; ++x) pv[t*3+x] = outv_pre[(n*D_F + t)*3 + x];
    __syncthreads();
    float acc = bo[t], a0 = 0.f, a1 = 0.f, a2 = 0.f;
    for (int i = 0; i < D_F; ++i) {
        float ws = Wo_s[i*D_F + t]; acc += ps[i]*ws;
        float wv = Wo_v[i*D_F + t];
        a0 += pv[i*3+0]*wv; a1 += pv[i*3+1]*wv; a2 += pv[i*3+2]*wv;
    }
    out0[n*D_F + t] = acc + skip_s[n*D_F + t];
    out1[(n*D_F + t)*3 + 0] = a0 + skip_v[(n*D_F + t)*3 + 0];
    out1[(n*D_F + t)*3 + 1] = a1 + skip_v[(n*D_F + t)*3 + 1];
    out1[(n*D_F + t)*3 + 2] = a2 + skip_v[(n*D_F + t)*3 + 2];
}

// ---------------------------------------------------------------------------
extern "C" void kernel_launch(void* const* d_in, const int* in_sizes, int n_in,
                              void* d_out, int out_size, void* d_ws, size_t ws_size,
                              hipStream_t stream)
{
    (void)in_sizes; (void)n_in; (void)out_size; (void)ws_size;

    const float* query_s = (const float*)d_in[0];
    const float* query_v = (const float*)d_in[1];
    const float* key_s   = (const float*)d_in[2];
    const float* key_v   = (const float*)d_in[3];
    const float* eis     = (const float*)d_in[4];
    const float* eiv     = (const float*)d_in[5];
    const float* eemb    = (const float*)d_in[6];
    const int*   mask    = (const int*)d_in[7];
    const int*   knn     = (const int*)d_in[8];
    const float* Wq_s    = (const float*)d_in[9];
    const float* Wq_v    = (const float*)d_in[10];
    const float* bq      = (const float*)d_in[11];
    const float* Wk_s    = (const float*)d_in[12];
    const float* Wk_v    = (const float*)d_in[13];
    const float* bk      = (const float*)d_in[14];
    const float* Wqk_s   = (const float*)d_in[15];
    const float* Wqk_v   = (const float*)d_in[16];
    const float* bqk     = (const float*)d_in[17];
    const float* Wdtp    = (const float*)d_in[18];
    const float* bdtp    = (const float*)d_in[19];
    const float* Wagv_s  = (const float*)d_in[20];
    const float* bagv    = (const float*)d_in[21];
    const float* Wagv_v  = (const float*)d_in[22];
    const float* Wattn   = (const float*)d_in[23];
    const float* Wval_s  = (const float*)d_in[24];
    const float* Wval_v  = (const float*)d_in[25];
    const float* bval    = (const float*)d_in[26];
    const float* Wo_s    = (const float*)d_in[27];
    const float* Wo_v    = (const float*)d_in[28];
    const float* bo      = (const float*)d_in[29];
    const float* ln_gs   = (const float*)d_in[30];
    const float* ln_bs   = (const float*)d_in[31];
    const float* ln_gv   = (const float*)d_in[32];
    const float* lna_g   = (const float*)d_in[33];
    const float* lna_b   = (const float*)d_in[34];

    float* out      = (float*)d_out;              // fp32 output!
    float* out_s    = out;                        // (B,N,D)
    float* out_v    = out + N_Q*D_F;              // (B,N,D,3)
    float* out_attn = out + N_Q*D_F*4;            // (H,B,N,K)

    float* ws = (float*)d_ws;
    float* qs2      = ws;                  // N*D
    float* qv2      = qs2 + N_Q*D_F;       // N*D*3
    float* ksc      = qv2 + N_Q*D_F*3;     // N*D
    float* kvc      = ksc + N_Q*D_F;       // N*D*3
    float* skip_s   = kvc + N_Q*D_F*3;     // N*D
    float* skip_v   = skip_s + N_Q*D_F;    // N*D*3
    float* outs_pre = skip_v + N_Q*D_F*3;  // N*D
    float* outv_pre = outs_pre + N_Q*D_F;  // N*D*3 (total 16*N*D floats = 16.8 MB)

    hipLaunchKernelGGL(k_query, dim3(N_Q), dim3(D_F), 0, stream,
                       query_s, query_v, Wq_s, Wq_v, bq, ln_gs, ln_bs, ln_gv,
                       qs2, qv2, skip_s, skip_v);
    hipLaunchKernelGGL(k_key, dim3(N_Q), dim3(D_F), 0, stream,
                       key_s, key_v, Wk_s, Wk_v, bk, ksc, kvc);
    hipLaunchKernelGGL(k_edge, dim3(N_Q), dim3(256), 0, stream,
                       qs2, qv2, ksc, kvc, eis, eiv, eemb, mask, knn,
                       Wqk_s, Wqk_v, bqk, Wdtp, bdtp,
                       Wagv_s, bagv, Wagv_v, Wattn, lna_g, lna_b,
                       Wval_s, Wval_v, bval,
                       outs_pre, outv_pre, out_attn);
    hipLaunchKernelGGL(k_out, dim3(N_Q), dim3(D_F), 0, stream,
                       outs_pre, outv_pre, skip_s, skip_v, Wo_s, Wo_v, bo,
                       out_s, out_v);
}

// Round 8
// 1333.163 us; speedup vs baseline: 1.3798x; 1.3798x over previous
//
#include <hip/hip_runtime.h>
#include <hip/hip_bf16.h>
#include <math.h>

#define N_Q 2048
#define K_E 32
#define D_F 128
#define H_N 8
#define DH_N 16
#define EPS_F 1e-5f
#define NEGMAX -3.4028235e38f

// dtypes (established rounds 0-7): float inputs, int32 mask/knn, FP32 output.

// ---------------------------------------------------------------------------
// Kernel A: query eq_layer_norm + eq_linear(Wq)
// ---------------------------------------------------------------------------
__global__ __launch_bounds__(128) void k_query(
    const float* __restrict__ qs_in, const float* __restrict__ qv_in,
    const float* __restrict__ Wq_s, const float* __restrict__ Wq_v,
    const float* __restrict__ bq,
    const float* __restrict__ ln_gs, const float* __restrict__ ln_bs,
    const float* __restrict__ ln_gv,
    float* __restrict__ qs2, float* __restrict__ qv2,
    float* __restrict__ skip_s, float* __restrict__ skip_v)
{
    const int n = blockIdx.x, t = threadIdx.x;
    __shared__ float s[D_F], v[D_F*3], sl[D_F], vl[D_F*3];
    s[t] = qs_in[n*D_F + t];
    #pragma unroll
    for (int x = 0; x < 3; ++x) v[t*3+x] = qv_in[(n*D_F + t)*3 + x];
    __syncthreads();
    float mu = 0.f;
    for (int i = 0; i < D_F; ++i) mu += s[i];
    mu *= (1.f/D_F);
    float var = 0.f;
    for (int i = 0; i < D_F; ++i) { float d = s[i]-mu; var += d*d; }
    var *= (1.f/D_F);
    float rstd = rsqrtf(var + EPS_F);
    float ssq = 0.f;
    for (int i = 0; i < D_F*3; ++i) ssq += v[i]*v[i];
    float rrms = rsqrtf(ssq*(1.f/D_F) + EPS_F);
    float a = (s[t]-mu)*rstd*ln_gs[t] + ln_bs[t];
    sl[t] = a; skip_s[n*D_F + t] = a;
    float gv = ln_gv[t];
    #pragma unroll
    for (int x = 0; x < 3; ++x) {
        float b = v[t*3+x]*rrms*gv;
        vl[t*3+x] = b; skip_v[(n*D_F + t)*3 + x] = b;
    }
    __syncthreads();
    float acc = bq[t], a0 = 0.f, a1 = 0.f, a2 = 0.f;
    for (int i = 0; i < D_F; ++i) {
        float ws = Wq_s[i*D_F + t]; acc += sl[i]*ws;
        float wv = Wq_v[i*D_F + t];
        a0 += vl[i*3+0]*wv; a1 += vl[i*3+1]*wv; a2 += vl[i*3+2]*wv;
    }
    qs2[n*D_F + t] = acc;
    qv2[(n*D_F + t)*3 + 0] = a0;
    qv2[(n*D_F + t)*3 + 1] = a1;
    qv2[(n*D_F + t)*3 + 2] = a2;
}

// ---------------------------------------------------------------------------
// Kernel B: key eq_linear(Wk)
// ---------------------------------------------------------------------------
__global__ __launch_bounds__(128) void k_key(
    const float* __restrict__ ks_in, const float* __restrict__ kv_in,
    const float* __restrict__ Wk_s, const float* __restrict__ Wk_v,
    const float* __restrict__ bk,
    float* __restrict__ ksc, float* __restrict__ kvc)
{
    const int n = blockIdx.x, t = threadIdx.x;
    __shared__ float s[D_F], v[D_F*3];
    s[t] = ks_in[n*D_F + t];
    #pragma unroll
    for (int x = 0; x < 3; ++x) v[t*3+x] = kv_in[(n*D_F + t)*3 + x];
    __syncthreads();
    float acc = bk[t], a0 = 0.f, a1 = 0.f, a2 = 0.f;
    for (int i = 0; i < D_F; ++i) {
        float ws = Wk_s[i*D_F + t]; acc += s[i]*ws;
        float wv = Wk_v[i*D_F + t];
        a0 += v[i*3+0]*wv; a1 += v[i*3+1]*wv; a2 += v[i*3+2]*wv;
    }
    ksc[n*D_F + t] = acc;
    kvc[(n*D_F + t)*3 + 0] = a0;
    kvc[(n*D_F + t)*3 + 1] = a1;
    kvc[(n*D_F + t)*3 + 2] = a2;
}

// ---------------------------------------------------------------------------
// Kernel C1: w = edge_emb @ Wdtp + bdtp for ALL edges (GEMM 65536x512x128).
// Block: 16 edges x 512 outs, 256 threads (2 outs, 16 edges each).
// ---------------------------------------------------------------------------
__global__ __launch_bounds__(256) void k_wgemm(
    const float* __restrict__ eemb, const float* __restrict__ Wdtp,
    const float* __restrict__ bdtp, float* __restrict__ wbuf)
{
    __shared__ float ee[D_F*16];          // transposed [i][m], 8 KB
    const int t = threadIdx.x;
    const int e0 = blockIdx.x * 16;
    #pragma unroll
    for (int r = 0; r < 8; ++r) {
        int idx = t + r*256;              // 0..2047
        int m = idx >> 7, i = idx & 127;
        ee[i*16 + m] = eemb[(size_t)(e0 + m)*D_F + i];
    }
    __syncthreads();
    const int o0 = t, o1 = t + 256;
    float acc0[16], acc1[16];
    const float b0 = bdtp[o0], b1 = bdtp[o1];
    #pragma unroll
    for (int m = 0; m < 16; ++m) { acc0[m] = b0; acc1[m] = b1; }
    for (int i = 0; i < D_F; ++i) {
        float w0 = Wdtp[i*512 + o0];
        float w1 = Wdtp[i*512 + o1];
        const float4* ep = (const float4*)&ee[i*16];
        #pragma unroll
        for (int q = 0; q < 4; ++q) {
            float4 e4 = ep[q];
            acc0[q*4+0] += e4.x*w0; acc1[q*4+0] += e4.x*w1;
            acc0[q*4+1] += e4.y*w0; acc1[q*4+1] += e4.y*w1;
            acc0[q*4+2] += e4.z*w0; acc1[q*4+2] += e4.z*w1;
            acc0[q*4+3] += e4.w*w0; acc1[q*4+3] += e4.w*w1;
        }
    }
    #pragma unroll
    for (int m = 0; m < 16; ++m) {
        wbuf[(size_t)(e0+m)*512 + o0] = acc0[m];
        wbuf[(size_t)(e0+m)*512 + o1] = acc1[m];
    }
}

// ---------------------------------------------------------------------------
// Kernel C2: edge pipeline with precomputed w. 128 threads/block (all live),
// online softmax, register accumulators. Bank-conflict-free head rotation.
// ---------------------------------------------------------------------------
__global__ __launch_bounds__(128) void k_edge2(
    const float* __restrict__ qs2, const float* __restrict__ qv2,
    const float* __restrict__ ksc, const float* __restrict__ kvc,
    const float* __restrict__ eis, const float* __restrict__ eiv,
    const float* __restrict__ wbuf,
    const int* __restrict__ mask, const int* __restrict__ knn,
    const float* __restrict__ Wqk_s, const float* __restrict__ Wqk_v, const float* __restrict__ bqk,
    const float* __restrict__ Wagv_s, const float* __restrict__ bagv, const float* __restrict__ Wagv_v,
    const float* __restrict__ Wattn, const float* __restrict__ lna_g, const float* __restrict__ lna_b,
    const float* __restrict__ Wval_s, const float* __restrict__ Wval_v, const float* __restrict__ bval,
    float* __restrict__ outs_pre, float* __restrict__ outv_pre,
    float* __restrict__ attn_out)
{
    const int n = blockIdx.x, t = threadIdx.x;
    const int h = t >> 4, o = t & 15;

    __shared__ float sh_qs[D_F], sh_qv[D_F*3];
    __shared__ float sh_ks[D_F], sh_kv[D_F*3];
    __shared__ float sh_cs[2*D_F], sh_cv[2*D_F*3];
    __shared__ float sh_ps[D_F], sh_pv[D_F*3];
    __shared__ float sh_w[512];
    __shared__ float sh_agv[H_N*48], sh_valv[D_F*3];
    __shared__ float sh_logit[H_N*K_E], sh_red[H_N*2];
    __shared__ float sh_es, sh_ev[3];

    sh_qs[t] = qs2[n*D_F + t];
    #pragma unroll
    for (int r = 0; r < 3; ++r) sh_qv[t + r*128] = qv2[n*D_F*3 + t + r*128];

    const float bqk_r  = bqk[o];
    const float bval_r = bval[o];
    const float bag0 = bagv[h*48 + o];
    const float bag1 = bagv[h*48 + 16 + o];
    const float bag2 = bagv[h*48 + 32 + o];

    float m_run = NEGMAX, l_run = 0.f;                    // used by t<8
    float accs = 0.f, acc0 = 0.f, acc1 = 0.f, acc2 = 0.f; // per-channel output acc

    const int tA = h*32 + o;        // concat2 channel, first half (i<16)
    const int tB = h*32 + 16 + o;   // second half
    const int cc = h*16 + o;        // per-head channel

    for (int k = 0; k < K_E; ++k) {
        const int e = n*K_E + k;
        const int j = knn[e];
        sh_ks[t] = ksc[j*D_F + t];
        #pragma unroll
        for (int r = 0; r < 3; ++r) sh_kv[t + r*128] = kvc[j*D_F*3 + t + r*128];
        #pragma unroll
        for (int r = 0; r < 4; ++r) sh_w[t + r*128] = wbuf[(size_t)e*512 + t + r*128];
        if (t == 0) {
            sh_es = eis[e];
            sh_ev[0] = eiv[e*3+0]; sh_ev[1] = eiv[e*3+1]; sh_ev[2] = eiv[e*3+2];
        }
        __syncthreads();

        // dtp1: cat c: [0,128)=ss/sv, [128,256)=vv/vs
        {
            float s1 = sh_qs[t], kd = sh_ks[t];
            float q0 = sh_qv[t*3+0], q1 = sh_qv[t*3+1], q2 = sh_qv[t*3+2];
            float k0 = sh_kv[t*3+0], k1 = sh_kv[t*3+1], k2 = sh_kv[t*3+2];
            sh_cs[t] = s1*kd;
            sh_cv[t*3+0] = s1*k0; sh_cv[t*3+1] = s1*k1; sh_cv[t*3+2] = s1*k2;
            sh_cs[D_F+t] = q0*k0 + q1*k1 + q2*k2;
            sh_cv[(D_F+t)*3+0] = kd*q0; sh_cv[(D_F+t)*3+1] = kd*q1; sh_cv[(D_F+t)*3+2] = kd*q2;
        }
        __syncthreads();

        // Wqk (head h, out o); i rotated per head to kill 4-way bank conflicts
        {
            float as = bqk_r, av0=0.f, av1=0.f, av2=0.f;
            for (int ii = 0; ii < 32; ++ii) {
                int i = (ii + h*8) & 31;
                int cb = h*32 + i;
                float ws = Wqk_s[i*16 + o];
                as += sh_cs[cb]*ws;
                float wv = Wqk_v[i*16 + o];
                av0 += sh_cv[cb*3+0]*wv; av1 += sh_cv[cb*3+1]*wv; av2 += sh_cv[cb*3+2]*wv;
            }
            sh_ps[t] = as;
            sh_pv[t*3+0] = av0; sh_pv[t*3+1] = av1; sh_pv[t*3+2] = av2;
        }
        __syncthreads();

        // dtp2 (weighted): w layout [sel*128 + h*16 + c]
        {
            float es = sh_es;
            float evx = sh_ev[0], evy = sh_ev[1], evz = sh_ev[2];
            float s1 = sh_ps[cc];
            float w0 = sh_w[cc], w1 = sh_w[128+cc], w2 = sh_w[256+cc], w3 = sh_w[384+cc];
            sh_cs[tA] = s1*es*w0;
            sh_cv[tA*3+0] = s1*evx*w2; sh_cv[tA*3+1] = s1*evy*w2; sh_cv[tA*3+2] = s1*evz*w2;
            float p0 = sh_pv[cc*3+0], p1 = sh_pv[cc*3+1], p2 = sh_pv[cc*3+2];
            sh_cs[tB] = (p0*evx + p1*evy + p2*evz)*w1;
            sh_cv[tB*3+0] = es*p0*w3; sh_cv[tB*3+1] = es*p1*w3; sh_cv[tB*3+2] = es*p2*w3;
        }
        __syncthreads();

        // Wagv: thread computes agv[h][{o,16+o,32+o}] and valv[h][o][3]
        {
            float aatt = bag0, agate = bag1, avals = bag2;
            float v0=0.f, v1=0.f, v2=0.f;
            for (int ii = 0; ii < 32; ++ii) {
                int i = (ii + h*8) & 31;
                int cb = h*32 + i;
                float a_s = sh_cs[cb];
                const float* wrow = &Wagv_s[(h*32+i)*48];
                aatt  += a_s*wrow[o];
                agate += a_s*wrow[16+o];
                avals += a_s*wrow[32+o];
                float wv = Wagv_v[(h*32+i)*16 + o];
                v0 += sh_cv[cb*3+0]*wv; v1 += sh_cv[cb*3+1]*wv; v2 += sh_cv[cb*3+2]*wv;
            }
            sh_agv[h*48+o] = aatt; sh_agv[h*48+16+o] = agate; sh_agv[h*48+32+o] = avals;
            sh_valv[t*3+0] = v0; sh_valv[t*3+1] = v1; sh_valv[t*3+2] = v2;
        }
        __syncthreads();

        // logit + online-softmax bookkeeping (t<8); silu/sigmoid gating (all)
        if (t < H_N) {
            const float* af = &sh_agv[t*48];
            float mu = 0.f;
            for (int d2 = 0; d2 < DH_N; ++d2) mu += af[d2];
            mu *= (1.f/DH_N);
            float var = 0.f;
            for (int d2 = 0; d2 < DH_N; ++d2) { float dd = af[d2]-mu; var += dd*dd; }
            var *= (1.f/DH_N);
            float rstd = rsqrtf(var + EPS_F);
            float logit = 0.f;
            for (int d2 = 0; d2 < DH_N; ++d2) {
                float xn = (af[d2]-mu)*rstd*lna_g[d2] + lna_b[d2];
                logit += xn*Wattn[d2];
            }
            if (mask[e] == 0) logit = NEGMAX;
            sh_logit[t*K_E + k] = logit;
            float m_new = fmaxf(m_run, logit);
            float alpha = expf(m_run - m_new);
            float p     = expf(logit - m_new);
            l_run = l_run*alpha + p;
            m_run = m_new;
            sh_red[t*2]   = alpha;
            sh_red[t*2+1] = p;
        }
        {
            float vraw = sh_agv[h*48 + 32 + o];
            float sact = vraw / (1.f + expf(-vraw));
            float g = 1.f / (1.f + expf(-sh_agv[h*48 + 16 + o]));
            sh_ps[t] = sact;
            sh_pv[t*3+0] = sh_valv[t*3+0]*g;
            sh_pv[t*3+1] = sh_valv[t*3+1]*g;
            sh_pv[t*3+2] = sh_valv[t*3+2]*g;
        }
        __syncthreads();

        // dtp3 (unweighted)
        {
            float es = sh_es;
            float evx = sh_ev[0], evy = sh_ev[1], evz = sh_ev[2];
            float s1 = sh_ps[cc];
            sh_cs[tA] = s1*es;
            sh_cv[tA*3+0] = s1*evx; sh_cv[tA*3+1] = s1*evy; sh_cv[tA*3+2] = s1*evz;
            float p0 = sh_pv[cc*3+0], p1 = sh_pv[cc*3+1], p2 = sh_pv[cc*3+2];
            sh_cs[tB] = p0*evx + p1*evy + p2*evz;
            sh_cv[tB*3+0] = es*p0; sh_cv[tB*3+1] = es*p1; sh_cv[tB*3+2] = es*p2;
        }
        __syncthreads();

        // Wval + flash accumulate
        {
            float vs = bval_r, v0=0.f, v1=0.f, v2=0.f;
            for (int ii = 0; ii < 32; ++ii) {
                int i = (ii + h*8) & 31;
                int cb = h*32 + i;
                float ws = Wval_s[i*16 + o];
                vs += sh_cs[cb]*ws;
                float wv = Wval_v[i*16 + o];
                v0 += sh_cv[cb*3+0]*wv; v1 += sh_cv[cb*3+1]*wv; v2 += sh_cv[cb*3+2]*wv;
            }
            float alpha = sh_red[h*2], p = sh_red[h*2+1];
            accs = accs*alpha + p*vs;
            acc0 = acc0*alpha + p*v0;
            acc1 = acc1*alpha + p*v1;
            acc2 = acc2*alpha + p*v2;
        }
        __syncthreads();   // protect sh_* before next iteration's staging
    }

    // epilogue
    if (t < H_N) {
        sh_red[t*2]   = m_run;
        sh_red[t*2+1] = 1.f / l_run;
    }
    __syncthreads();
    #pragma unroll
    for (int r = 0; r < 2; ++r) {
        int idx = t + r*128;
        int hh = idx >> 5, kk = idx & 31;
        attn_out[hh*(N_Q*K_E) + n*K_E + kk] =
            expf(sh_logit[idx] - sh_red[hh*2]) * sh_red[hh*2+1];
    }
    {
        float rinv = sh_red[h*2+1];
        outs_pre[n*D_F + t]     = accs*rinv;
        outv_pre[(n*D_F+t)*3+0] = acc0*rinv;
        outv_pre[(n*D_F+t)*3+1] = acc1*rinv;
        outv_pre[(n*D_F+t)*3+2] = acc2*rinv;
    }
}

// ---------------------------------------------------------------------------
// Fallback (round-7 monolithic k_edge) for small ws_size
// ---------------------------------------------------------------------------
__global__ __launch_bounds__(256) void k_edge(
    const float* __restrict__ qs2, const float* __restrict__ qv2,
    const float* __restrict__ ksc, const float* __restrict__ kvc,
    const float* __restrict__ eis, const float* __restrict__ eiv,
    const float* __restrict__ eemb,
    const int* __restrict__ mask, const int* __restrict__ knn,
    const float* __restrict__ Wqk_s, const float* __restrict__ Wqk_v, const float* __restrict__ bqk,
    const float* __restrict__ Wdtp, const float* __restrict__ bdtp,
    const float* __restrict__ Wagv_s, const float* __restrict__ bagv, const float* __restrict__ Wagv_v,
    const float* __restrict__ Wattn, const float* __restrict__ lna_g, const float* __restrict__ lna_b,
    const float* __restrict__ Wval_s, const float* __restrict__ Wval_v, const float* __restrict__ bval,
    float* __restrict__ outs_pre, float* __restrict__ outv_pre,
    float* __restrict__ attn_out)
{
    const int n = blockIdx.x, t = threadIdx.x;
    __shared__ float sh_qs[D_F], sh_qv[D_F*3];
    __shared__ float sh_ks[D_F], sh_kv[D_F*3], sh_ee[D_F];
    __shared__ float sh_cs[2*D_F], sh_cv[2*D_F*3];
    __shared__ float sh_ps[D_F], sh_pv[D_F*3];
    __shared__ float sh_w[4*D_F];
    __shared__ float sh_agv[H_N*48], sh_valv[H_N*DH_N*3];
    __shared__ float sh_logit[H_N*K_E], sh_red[H_N*2];
    __shared__ float sh_es, sh_ev[3];
    float m_run = NEGMAX, l_run = 0.f;
    float accs = 0.f, acc0 = 0.f, acc1 = 0.f, acc2 = 0.f;
    if (t < D_F) sh_qs[t] = qs2[n*D_F + t];
    for (int idx = t; idx < D_F*3; idx += 256) sh_qv[idx] = qv2[n*D_F*3 + idx];
    for (int k = 0; k < K_E; ++k) {
        const int e = n*K_E + k;
        const int j = knn[e];
        if (t < D_F) { sh_ks[t] = ksc[j*D_F + t]; sh_ee[t] = eemb[e*D_F + t]; }
        for (int idx = t; idx < D_F*3; idx += 256) sh_kv[idx] = kvc[j*D_F*3 + idx];
        if (t == 0) {
            sh_es = eis[e];
            sh_ev[0] = eiv[e*3+0]; sh_ev[1] = eiv[e*3+1]; sh_ev[2] = eiv[e*3+2];
        }
        __syncthreads();
        {
            const int c = t;
            if (c < D_F) {
                float s1 = sh_qs[c];
                sh_cs[c] = s1 * sh_ks[c];
                #pragma unroll
                for (int x = 0; x < 3; ++x) sh_cv[c*3+x] = s1 * sh_kv[c*3+x];
            } else {
                int d = c - D_F;
                float dot = 0.f;
                #pragma unroll
                for (int x = 0; x < 3; ++x) dot += sh_qv[d*3+x]*sh_kv[d*3+x];
                sh_cs[c] = dot;
                #pragma unroll
                for (int x = 0; x < 3; ++x) sh_cv[c*3+x] = sh_ks[d]*sh_qv[d*3+x];
            }
        }
        __syncthreads();
        #pragma unroll
        for (int r = 0; r < 2; ++r) {
            int oo = t + r*256;
            float acc = bdtp[oo];
            for (int i = 0; i < D_F; ++i) acc += sh_ee[i]*Wdtp[i*512 + oo];
            sh_w[oo] = acc;
        }
        if (t < D_F) {
            int h = t >> 4, o = t & 15;
            float as = bqk[o], av0 = 0.f, av1 = 0.f, av2 = 0.f;
            for (int i = 0; i < 32; ++i) {
                int cb = h*32 + i;
                float ws = Wqk_s[i*16 + o];
                as += sh_cs[cb]*ws;
                float wv = Wqk_v[i*16 + o];
                av0 += sh_cv[cb*3+0]*wv; av1 += sh_cv[cb*3+1]*wv; av2 += sh_cv[cb*3+2]*wv;
            }
            sh_ps[t] = as;
            sh_pv[t*3+0] = av0; sh_pv[t*3+1] = av1; sh_pv[t*3+2] = av2;
        }
        __syncthreads();
        {
            int h = t >> 5, i = t & 31;
            float es = sh_es;
            if (i < DH_N) {
                int cc = h*DH_N + i;
                float s1 = sh_ps[cc];
                sh_cs[t] = s1*es*sh_w[0*D_F + cc];
                float w2 = sh_w[2*D_F + cc];
                #pragma unroll
                for (int x = 0; x < 3; ++x) sh_cv[t*3+x] = s1*sh_ev[x]*w2;
            } else {
                int cc = h*DH_N + (i - DH_N);
                float dot = 0.f;
                #pragma unroll
                for (int x = 0; x < 3; ++x) dot += sh_pv[cc*3+x]*sh_ev[x];
                sh_cs[t] = dot*sh_w[1*D_F + cc];
                float w3 = sh_w[3*D_F + cc];
                #pragma unroll
                for (int x = 0; x < 3; ++x) sh_cv[t*3+x] = es*sh_pv[cc*3+x]*w3;
            }
        }
        __syncthreads();
        for (int idx = t; idx < H_N*48; idx += 256) {
            int h = idx / 48, oo = idx % 48;
            float acc = bagv[h*48 + oo];
            for (int i = 0; i < 32; ++i)
                acc += sh_cs[h*32 + i]*Wagv_s[(h*32 + i)*48 + oo];
            sh_agv[idx] = acc;
        }
        if (t < D_F) {
            int h = t >> 4, o = t & 15;
            float a0 = 0.f, a1 = 0.f, a2 = 0.f;
            for (int i = 0; i < 32; ++i) {
                float wv = Wagv_v[(h*32 + i)*16 + o];
                a0 += sh_cv[(h*32+i)*3+0]*wv;
                a1 += sh_cv[(h*32+i)*3+1]*wv;
                a2 += sh_cv[(h*32+i)*3+2]*wv;
            }
            sh_valv[t*3+0] = a0; sh_valv[t*3+1] = a1; sh_valv[t*3+2] = a2;
        }
        __syncthreads();
        if (t < H_N) {
            const float* af = &sh_agv[t*48];
            float mu = 0.f;
            for (int d2 = 0; d2 < DH_N; ++d2) mu += af[d2];
            mu *= (1.f/DH_N);
            float var = 0.f;
            for (int d2 = 0; d2 < DH_N; ++d2) { float dd = af[d2]-mu; var += dd*dd; }
            var *= (1.f/DH_N);
            float rstd = rsqrtf(var + EPS_F);
            float logit = 0.f;
            for (int d2 = 0; d2 < DH_N; ++d2) {
                float xn = (af[d2]-mu)*rstd*lna_g[d2] + lna_b[d2];
                logit += xn*Wattn[d2];
            }
            if (mask[e] == 0) logit = NEGMAX;
            sh_logit[t*K_E + k] = logit;
            float m_new = fmaxf(m_run, logit);
            float alpha = expf(m_run - m_new);
            float p     = expf(logit - m_new);
            l_run = l_run*alpha + p;
            m_run = m_new;
            sh_red[t*2]   = alpha;
            sh_red[t*2+1] = p;
        }
        if (t < D_F) {
            int h = t >> 4, o = t & 15;
            float vraw = sh_agv[h*48 + 32 + o];
            float sact = vraw / (1.f + expf(-vraw));
            float g = 1.f / (1.f + expf(-sh_agv[h*48 + 16 + o]));
            sh_ps[t] = sact;
            #pragma unroll
            for (int x = 0; x < 3; ++x) sh_pv[t*3+x] = sh_valv[t*3+x]*g;
        }
        __syncthreads();
        {
            int h = t >> 5, i = t & 31;
            if (i < DH_N) {
                int cc = h*DH_N + i;
                float s1 = sh_ps[cc];
                sh_cs[t] = s1*sh_es;
                #pragma unroll
                for (int x = 0; x < 3; ++x) sh_cv[t*3+x] = s1*sh_ev[x];
            } else {
                int cc = h*DH_N + (i - DH_N);
                float dot = 0.f;
                #pragma unroll
                for (int x = 0; x < 3; ++x) dot += sh_pv[cc*3+x]*sh_ev[x];
                sh_cs[t] = dot;
                #pragma unroll
                for (int x = 0; x < 3; ++x) sh_cv[t*3+x] = sh_es*sh_pv[cc*3+x];
            }
        }
        __syncthreads();
        if (t < D_F) {
            int h = t >> 4, o = t & 15;
            float vs = bval[o], v0 = 0.f, v1 = 0.f, v2 = 0.f;
            for (int i = 0; i < 32; ++i) {
                int cb = h*32 + i;
                float ws = Wval_s[i*16 + o];
                vs += sh_cs[cb]*ws;
                float wv = Wval_v[i*16 + o];
                v0 += sh_cv[cb*3+0]*wv; v1 += sh_cv[cb*3+1]*wv; v2 += sh_cv[cb*3+2]*wv;
            }
            float alpha = sh_red[h*2], p = sh_red[h*2+1];
            accs = accs*alpha + p*vs;
            acc0 = acc0*alpha + p*v0;
            acc1 = acc1*alpha + p*v1;
            acc2 = acc2*alpha + p*v2;
        }
        __syncthreads();
    }
    if (t < H_N) {
        sh_red[t*2]   = m_run;
        sh_red[t*2+1] = 1.f / l_run;
    }
    __syncthreads();
    {
        int h = t >> 5, k = t & 31;
        float a = expf(sh_logit[t] - sh_red[h*2]) * sh_red[h*2+1];
        attn_out[h*(N_Q*K_E) + n*K_E + k] = a;
    }
    if (t < D_F) {
        int h = t >> 4;
        float rinv = sh_red[h*2+1];
        outs_pre[n*D_F + t]     = accs*rinv;
        outv_pre[(n*D_F+t)*3+0] = acc0*rinv;
        outv_pre[(n*D_F+t)*3+1] = acc1*rinv;
        outv_pre[(n*D_F+t)*3+2] = acc2*rinv;
    }
}

// ---------------------------------------------------------------------------
// Kernel D: output eq_linear(Wo) + skip add
// ---------------------------------------------------------------------------
__global__ __launch_bounds__(128) void k_out(
    const float* __restrict__ outs_pre, const float* __restrict__ outv_pre,
    const float* __restrict__ skip_s, const float* __restrict__ skip_v,
    const float* __restrict__ Wo_s, const float* __restrict__ Wo_v, const float* __restrict__ bo,
    float* __restrict__ out0, float* __restrict__ out1)
{
    const int n = blockIdx.x, t = threadIdx.x;
    __shared__ float ps[D_F], pv[D_F*3];
    ps[t] = outs_pre[n*D_F + t];
    #pragma unroll
    for (int x = 0; x < 3; ++x) pv[t*3+x] = outv_pre[(n*D_F + t)*3 + x];
    __syncthreads();
    float acc = bo[t], a0 = 0.f, a1 = 0.f, a2 = 0.f;
    for (int i = 0; i < D_F; ++i) {
        float ws = Wo_s[i*D_F + t]; acc += ps[i]*ws;
        float wv = Wo_v[i*D_F + t];
        a0 += pv[i*3+0]*wv; a1 += pv[i*3+1]*wv; a2 += pv[i*3+2]*wv;
    }
    out0[n*D_F + t] = acc + skip_s[n*D_F + t];
    out1[(n*D_F + t)*3 + 0] = a0 + skip_v[(n*D_F + t)*3 + 0];
    out1[(n*D_F + t)*3 + 1] = a1 + skip_v[(n*D_F + t)*3 + 1];
    out1[(n*D_F + t)*3 + 2] = a2 + skip_v[(n*D_F + t)*3 + 2];
}

// ---------------------------------------------------------------------------
extern "C" void kernel_launch(void* const* d_in, const int* in_sizes, int n_in,
                              void* d_out, int out_size, void* d_ws, size_t ws_size,
                              hipStream_t stream)
{
    (void)in_sizes; (void)n_in; (void)out_size;

    const float* query_s = (const float*)d_in[0];
    const float* query_v = (const float*)d_in[1];
    const float* key_s   = (const float*)d_in[2];
    const float* key_v   = (const float*)d_in[3];
    const float* eis     = (const float*)d_in[4];
    const float* eiv     = (const float*)d_in[5];
    const float* eemb    = (const float*)d_in[6];
    const int*   mask    = (const int*)d_in[7];
    const int*   knn     = (const int*)d_in[8];
    const float* Wq_s    = (const float*)d_in[9];
    const float* Wq_v    = (const float*)d_in[10];
    const float* bq      = (const float*)d_in[11];
    const float* Wk_s    = (const float*)d_in[12];
    const float* Wk_v    = (const float*)d_in[13];
    const float* bk      = (const float*)d_in[14];
    const float* Wqk_s   = (const float*)d_in[15];
    const float* Wqk_v   = (const float*)d_in[16];
    const float* bqk     = (const float*)d_in[17];
    const float* Wdtp    = (const float*)d_in[18];
    const float* bdtp    = (const float*)d_in[19];
    const float* Wagv_s  = (const float*)d_in[20];
    const float* bagv    = (const float*)d_in[21];
    const float* Wagv_v  = (const float*)d_in[22];
    const float* Wattn   = (const float*)d_in[23];
    const float* Wval_s  = (const float*)d_in[24];
    const float* Wval_v  = (const float*)d_in[25];
    const float* bval    = (const float*)d_in[26];
    const float* Wo_s    = (const float*)d_in[27];
    const float* Wo_v    = (const float*)d_in[28];
    const float* bo      = (const float*)d_in[29];
    const float* ln_gs   = (const float*)d_in[30];
    const float* ln_bs   = (const float*)d_in[31];
    const float* ln_gv   = (const float*)d_in[32];
    const float* lna_g   = (const float*)d_in[33];
    const float* lna_b   = (const float*)d_in[34];

    float* out      = (float*)d_out;
    float* out_s    = out;
    float* out_v    = out + N_Q*D_F;
    float* out_attn = out + N_Q*D_F*4;

    float* ws = (float*)d_ws;
    float* qs2      = ws;
    float* qv2      = qs2 + N_Q*D_F;
    float* ksc      = qv2 + N_Q*D_F*3;
    float* kvc      = ksc + N_Q*D_F;
    float* skip_s   = kvc + N_Q*D_F*3;
    float* skip_v   = skip_s + N_Q*D_F;
    float* outs_pre = skip_v + N_Q*D_F*3;
    float* outv_pre = outs_pre + N_Q*D_F;
    float* wbuf     = outv_pre + N_Q*D_F*3;       // N*K*512 floats = 134.2 MB

    const size_t base_floats = (size_t)16*N_Q*D_F;
    const size_t wbuf_floats = (size_t)N_Q*K_E*512;
    const bool   use_gemm = ws_size >= (base_floats + wbuf_floats)*sizeof(float);

    hipLaunchKernelGGL(k_query, dim3(N_Q), dim3(D_F), 0, stream,
                       query_s, query_v, Wq_s, Wq_v, bq, ln_gs, ln_bs, ln_gv,
                       qs2, qv2, skip_s, skip_v);
    hipLaunchKernelGGL(k_key, dim3(N_Q), dim3(D_F), 0, stream,
                       key_s, key_v, Wk_s, Wk_v, bk, ksc, kvc);
    if (use_gemm) {
        hipLaunchKernelGGL(k_wgemm, dim3(N_Q*K_E/16), dim3(256), 0, stream,
                           eemb, Wdtp, bdtp, wbuf);
        hipLaunchKernelGGL(k_edge2, dim3(N_Q), dim3(128), 0, stream,
                           qs2, qv2, ksc, kvc, eis, eiv, wbuf, mask, knn,
                           Wqk_s, Wqk_v, bqk,
                           Wagv_s, bagv, Wagv_v, Wattn, lna_g, lna_b,
                           Wval_s, Wval_v, bval,
                           outs_pre, outv_pre, out_attn);
    } else {
        hipLaunchKernelGGL(k_edge, dim3(N_Q), dim3(256), 0, stream,
                           qs2, qv2, ksc, kvc, eis, eiv, eemb, mask, knn,
                           Wqk_s, Wqk_v, bqk, Wdtp, bdtp,
                           Wagv_s, bagv, Wagv_v, Wattn, lna_g, lna_b,
                           Wval_s, Wval_v, bval,
                           outs_pre, outv_pre, out_attn);
    }
    hipLaunchKernelGGL(k_out, dim3(N_Q), dim3(D_F), 0, stream,
                       outs_pre, outv_pre, skip_s, skip_v, Wo_s, Wo_v, bo,
                       out_s, out_v);
}